// Round 1
// baseline (61.547 us; speedup 1.0000x reference)
//
#include <hip/hip_runtime.h>

// MVDR attention: per (b,t,f) cell solve Phi_N * Y = Phi_S (5x5 complex,
// Gauss-Jordan with partial pivoting done via unrolled predicated swaps),
// then W = Y[:,0]/(tr(Y)+eps(1+i)), S_hat = sum_m conj(W_m) x_m.
// Output layout (B,F,T,2).

constexpr int MD = 5;
constexpr int BB = 2, TT = 600, FF = 513;
constexpr int TOTAL = BB * TT * FF;

__global__ __launch_bounds__(256) void mvdr_kernel(
    const float* __restrict__ spec,    // (B,T,F,M,2)
    const float* __restrict__ corrS,   // (B,T,F,M,M,2)
    const float* __restrict__ corrN,   // (B,T,F,M,M,2)
    float* __restrict__ out)           // (B,F,T,2)
{
    int idx = blockIdx.x * blockDim.x + threadIdx.x;
    if (idx >= TOTAL) return;
    int f  = idx % FF;
    int bt = idx / FF;
    int t  = bt % TT;
    int b  = bt / TT;

    float Nr[MD][MD], Ni[MD][MD], Sr[MD][MD], Si[MD][MD];

    const float2* __restrict__ pn = reinterpret_cast<const float2*>(corrN) + (size_t)idx * (MD * MD);
    const float2* __restrict__ ps = reinterpret_cast<const float2*>(corrS) + (size_t)idx * (MD * MD);

#pragma unroll
    for (int i = 0; i < MD; ++i) {
#pragma unroll
        for (int j = 0; j < MD; ++j) {
            float2 v = pn[i * MD + j];
            Nr[i][j] = v.x; Ni[i][j] = v.y;
            float2 w = ps[i * MD + j];
            Sr[i][j] = w.x; Si[i][j] = w.y;
        }
    }
#pragma unroll
    for (int i = 0; i < MD; ++i) { Nr[i][i] += 1e-7f; Ni[i][i] += 1e-7f; }

    // Gauss-Jordan: reduce [N | S] -> [I | N^-1 S]. Partial pivoting via
    // compile-time-unrolled predicated row swaps (no runtime reg indexing).
#pragma unroll
    for (int k = 0; k < MD; ++k) {
#pragma unroll
        for (int j = k + 1; j < MD; ++j) {
            bool sw = (Nr[j][k] * Nr[j][k] + Ni[j][k] * Ni[j][k]) >
                      (Nr[k][k] * Nr[k][k] + Ni[k][k] * Ni[k][k]);
#pragma unroll
            for (int c = k; c < MD; ++c) {
                float ta, tb;
                ta = Nr[k][c]; tb = Nr[j][c];
                Nr[k][c] = sw ? tb : ta; Nr[j][c] = sw ? ta : tb;
                ta = Ni[k][c]; tb = Ni[j][c];
                Ni[k][c] = sw ? tb : ta; Ni[j][c] = sw ? ta : tb;
            }
#pragma unroll
            for (int c = 0; c < MD; ++c) {
                float ta, tb;
                ta = Sr[k][c]; tb = Sr[j][c];
                Sr[k][c] = sw ? tb : ta; Sr[j][c] = sw ? ta : tb;
                ta = Si[k][c]; tb = Si[j][c];
                Si[k][c] = sw ? tb : ta; Si[j][c] = sw ? ta : tb;
            }
        }
        // pivot reciprocal: 1/p = conj(p)/|p|^2
        float pr = Nr[k][k], pi = Ni[k][k];
        float invd = 1.0f / (pr * pr + pi * pi);
        float ipr = pr * invd, ipi = -pi * invd;
        // scale pivot row
#pragma unroll
        for (int c = k + 1; c < MD; ++c) {
            float xr = Nr[k][c], xi = Ni[k][c];
            Nr[k][c] = xr * ipr - xi * ipi;
            Ni[k][c] = xr * ipi + xi * ipr;
        }
#pragma unroll
        for (int c = 0; c < MD; ++c) {
            float xr = Sr[k][c], xi = Si[k][c];
            Sr[k][c] = xr * ipr - xi * ipi;
            Si[k][c] = xr * ipi + xi * ipr;
        }
        // eliminate all other rows
#pragma unroll
        for (int i = 0; i < MD; ++i) {
            if (i == k) continue;
            float fr = Nr[i][k], fi = Ni[i][k];
#pragma unroll
            for (int c = k + 1; c < MD; ++c) {
                float xr = Nr[k][c], xi = Ni[k][c];
                Nr[i][c] -= fr * xr - fi * xi;
                Ni[i][c] -= fr * xi + fi * xr;
            }
#pragma unroll
            for (int c = 0; c < MD; ++c) {
                float xr = Sr[k][c], xi = Si[k][c];
                Sr[i][c] -= fr * xr - fi * xi;
                Si[i][c] -= fr * xi + fi * xr;
            }
        }
    }

    // trace(Y) + eps(1+i)
    float trr = 0.f, tri = 0.f;
#pragma unroll
    for (int i = 0; i < MD; ++i) { trr += Sr[i][i]; tri += Si[i][i]; }
    const float eps = 1.1920929e-07f;
    trr += eps; tri += eps;

    // z = sum_m conj(a1[m]) * x[m],  a1[m] = Y[m][0]
    const float2* __restrict__ px = reinterpret_cast<const float2*>(spec) + (size_t)idx * MD;
    float zr = 0.f, zi = 0.f;
#pragma unroll
    for (int m = 0; m < MD; ++m) {
        float2 x = px[m];
        float ar = Sr[m][0], ai = -Si[m][0];   // conj(a1)
        zr += ar * x.x - ai * x.y;
        zi += ar * x.y + ai * x.x;
    }

    // S_hat = z / conj(d) = z * (trr + i*tri) / |d|^2
    float inv2 = 1.0f / (trr * trr + tri * tri);
    float shr = (zr * trr - zi * tri) * inv2;
    float shi = (zr * tri + zi * trr) * inv2;

    float2* __restrict__ po = reinterpret_cast<float2*>(out);
    po[((size_t)b * FF + f) * TT + t] = make_float2(shr, shi);
}

extern "C" void kernel_launch(void* const* d_in, const int* in_sizes, int n_in,
                              void* d_out, int out_size, void* d_ws, size_t ws_size,
                              hipStream_t stream) {
    const float* spec  = (const float*)d_in[0];
    const float* corrS = (const float*)d_in[1];
    const float* corrN = (const float*)d_in[2];
    float* out = (float*)d_out;

    int blocks = (TOTAL + 255) / 256;
    mvdr_kernel<<<blocks, 256, 0, stream>>>(spec, corrS, corrN, out);
}